// Round 1
// baseline (583.798 us; speedup 1.0000x reference)
//
#include <hip/hip_runtime.h>
#include <math.h>

#define LEAKY(x) ((x) >= 0.0f ? (x) : 0.2f * (x))

// ---------------------------------------------------------------------------
// Kernel 1: xp = x @ W  (N x 128) = (N x 128)(128 x 128), fused with
// attn_self / attn_neigh = einsum('nhc,ch->nh').
// Block = 256 threads handles 32 nodes; x tile staged in LDS (padded).
// ---------------------------------------------------------------------------
__global__ __launch_bounds__(256) void gemm_attn(
    const float* __restrict__ x, const float* __restrict__ W,
    const float* __restrict__ aks, const float* __restrict__ akn,
    float* __restrict__ xp, float* __restrict__ attn_self,
    float* __restrict__ attn_nei, int N)
{
    __shared__ float xs[32][132];
    const int t  = threadIdx.x;
    const int nb = blockIdx.x * 32;

    #pragma unroll
    for (int k = 0; k < 16; ++k) {
        int idx = t + k * 256;
        int n = idx >> 7, f = idx & 127;
        xs[n][f] = (nb + n < N) ? x[(size_t)(nb + n) * 128 + f] : 0.0f;
    }
    __syncthreads();

    const int c4 = (t & 31) * 4;     // output column quad (h*32+c)
    const int g  = (t >> 5) * 4;     // first of 4 nodes this thread owns
    float acc[4][4] = {};
    for (int f = 0; f < 128; ++f) {
        const float4 w = *(const float4*)&W[f * 128 + c4];
        #pragma unroll
        for (int i = 0; i < 4; ++i) {
            float xv = xs[g + i][f];
            acc[i][0] = fmaf(xv, w.x, acc[i][0]);
            acc[i][1] = fmaf(xv, w.y, acc[i][1]);
            acc[i][2] = fmaf(xv, w.z, acc[i][2]);
            acc[i][3] = fmaf(xv, w.w, acc[i][3]);
        }
    }
    #pragma unroll
    for (int i = 0; i < 4; ++i) {
        int n = nb + g + i;
        if (n < N)
            *(float4*)&xp[(size_t)n * 128 + c4] =
                make_float4(acc[i][0], acc[i][1], acc[i][2], acc[i][3]);
    }
    __syncthreads();            // everyone done reading x tile
    #pragma unroll
    for (int i = 0; i < 4; ++i) {
        xs[g + i][c4 + 0] = acc[i][0];
        xs[g + i][c4 + 1] = acc[i][1];
        xs[g + i][c4 + 2] = acc[i][2];
        xs[g + i][c4 + 3] = acc[i][3];
    }
    __syncthreads();
    if (t < 128) {
        int n = t >> 2, h = t & 3;
        if (nb + n < N) {
            float ss = 0.0f, sn = 0.0f;
            #pragma unroll
            for (int c = 0; c < 32; ++c) {
                float v = xs[n][h * 32 + c];
                ss = fmaf(v, aks[c * 4 + h], ss);
                sn = fmaf(v, akn[c * 4 + h], sn);
            }
            attn_self[(size_t)(nb + n) * 4 + h] = ss;
            attn_nei [(size_t)(nb + n) * 4 + h] = sn;
        }
    }
}

// ---------------------------------------------------------------------------
// CSR build: histogram -> scan (3 kernels) -> fill
// ---------------------------------------------------------------------------
__global__ void hist_kernel(const int* __restrict__ ei, int* __restrict__ counts, int E)
{
    const int i = blockIdx.x * 256 + threadIdx.x;
    if (i < E) atomicAdd(&counts[ei[2 * (size_t)i + 1]], 1);
}

__global__ __launch_bounds__(256) void scan1(
    const int* __restrict__ counts, int* __restrict__ offsets,
    int* __restrict__ tileSums, int N)
{
    __shared__ int sdata[256];
    const int t = threadIdx.x;
    const int i0 = blockIdx.x * 1024 + t * 4;
    int v[4];
    #pragma unroll
    for (int k = 0; k < 4; ++k) v[k] = (i0 + k < N) ? counts[i0 + k] : 0;
    v[1] += v[0]; v[2] += v[1]; v[3] += v[2];
    const int tot = v[3];
    sdata[t] = tot;
    __syncthreads();
    for (int d = 1; d < 256; d <<= 1) {
        int add = (t >= d) ? sdata[t - d] : 0;
        __syncthreads();
        sdata[t] += add;
        __syncthreads();
    }
    const int excl = sdata[t] - tot;
    #pragma unroll
    for (int k = 0; k < 4; ++k) {
        int i = i0 + k;
        if (i < N) offsets[i + 1] = excl + v[k];
    }
    if (t == 255) tileSums[blockIdx.x] = sdata[255];
}

__global__ void scan2(const int* __restrict__ tileSums, int* __restrict__ tileOffs, int numTiles)
{
    if (threadIdx.x == 0 && blockIdx.x == 0) {
        int run = 0;
        for (int i = 0; i < numTiles; ++i) { tileOffs[i] = run; run += tileSums[i]; }
        tileOffs[numTiles] = run;
    }
}

__global__ void scan3(int* __restrict__ offsets, const int* __restrict__ tileOffs, int N)
{
    const int i = blockIdx.x * 256 + threadIdx.x;
    if (i == 0) offsets[0] = 0;
    if (i < N) offsets[i + 1] += tileOffs[i >> 10];
}

__global__ void fill_kernel(const int* __restrict__ ei, const int* __restrict__ offsets,
                            int* __restrict__ cursor, int* __restrict__ edge_list, int E)
{
    const int i = blockIdx.x * 256 + threadIdx.x;
    if (i >= E) return;
    int tgt  = ei[2 * (size_t)i + 1];
    int slot = atomicAdd(&cursor[tgt], 1);
    edge_list[offsets[tgt] + slot] = i;
}

// ---------------------------------------------------------------------------
// Kernel 3: one wave per node. Pass A (lane-parallel): softmax max incl. the
// implicit self-loop. Pass B (serial over edges, lanes = 128 channels):
// acc += e * xp[src]; out = acc / sum(e) + bias. Writes per-node (M, 1/sum)
// tables and the self-loop alpha.
// ---------------------------------------------------------------------------
__global__ __launch_bounds__(256) void aggregate(
    const int* __restrict__ ei, const int* __restrict__ offsets,
    const int* __restrict__ edge_list, const float* __restrict__ xp,
    const float* __restrict__ attn_self, const float* __restrict__ attn_nei,
    const float* __restrict__ bias, float* __restrict__ out,
    float* __restrict__ alpha_out, float* __restrict__ m_arr,
    float* __restrict__ inv_arr, int N, int E)
{
    const int lane = threadIdx.x & 63;
    const int node = blockIdx.x * 4 + (threadIdx.x >> 6);
    if (node >= N) return;

    const float4 as4 = *(const float4*)&attn_self[(size_t)node * 4];
    const float4 an4 = *(const float4*)&attn_nei[(size_t)node * 4];
    const float asv[4] = {as4.x, as4.y, as4.z, as4.w};
    const float anv[4] = {an4.x, an4.y, an4.z, an4.w};
    float selfL[4], mx[4];
    #pragma unroll
    for (int h = 0; h < 4; ++h) { selfL[h] = LEAKY(asv[h] + anv[h]); mx[h] = selfL[h]; }

    const int off0 = offsets[node];
    const int deg  = offsets[node + 1] - off0;

    // pass A: per-head max over incident edges (lane-parallel)
    for (int i = lane; i < deg; i += 64) {
        int e   = edge_list[off0 + i];
        int src = ei[2 * (size_t)e];
        float4 an = *(const float4*)&attn_nei[(size_t)src * 4];
        float av[4] = {an.x, an.y, an.z, an.w};
        #pragma unroll
        for (int h = 0; h < 4; ++h) mx[h] = fmaxf(mx[h], LEAKY(asv[h] + av[h]));
    }
    #pragma unroll
    for (int h = 0; h < 4; ++h) {
        #pragma unroll
        for (int d = 1; d < 64; d <<= 1) mx[h] = fmaxf(mx[h], __shfl_xor(mx[h], d));
    }

    const int hL = lane >> 4;        // head of this lane's 2 channels
    const int c0 = 2 * lane;
    const float M   = mx[hL];
    const float asH = asv[hL];
    const float eS  = expf(selfL[hL] - M);
    float sumE = eS;
    const float2 xv = *(const float2*)&xp[(size_t)node * 128 + c0];
    float acc0 = eS * xv.x, acc1 = eS * xv.y;

    // pass B: serial over edges, all lanes cooperate on channels
    for (int j = 0; j < deg; ++j) {
        int e   = edge_list[off0 + j];
        int src = ei[2 * (size_t)e];
        float an = attn_nei[(size_t)src * 4 + hL];
        float ev = expf(LEAKY(asH + an) - M);
        sumE += ev;
        const float2 xs2 = *(const float2*)&xp[(size_t)src * 128 + c0];
        acc0 = fmaf(ev, xs2.x, acc0);
        acc1 = fmaf(ev, xs2.y, acc1);
    }
    const float inv = 1.0f / sumE;
    *(float2*)&out[(size_t)node * 128 + c0] =
        make_float2(fmaf(acc0, inv, bias[c0]), fmaf(acc1, inv, bias[c0 + 1]));
    if ((lane & 15) == 0) {
        m_arr  [(size_t)node * 4 + hL] = M;
        inv_arr[(size_t)node * 4 + hL] = inv;
        alpha_out[(size_t)(E + node) * 4 + hL] = eS * inv;   // self-loop alpha
    }
}

// ---------------------------------------------------------------------------
// Kernel 4: alpha for the E real edges, fully coalesced by edge id.
// ---------------------------------------------------------------------------
__global__ __launch_bounds__(256) void alpha_kernel(
    const int* __restrict__ ei, const float* __restrict__ attn_self,
    const float* __restrict__ attn_nei, const float* __restrict__ m_arr,
    const float* __restrict__ inv_arr, float* __restrict__ alpha_out, int E)
{
    const int i = blockIdx.x * 256 + threadIdx.x;
    if (i >= E) return;
    const int2 e2 = *(const int2*)&ei[2 * (size_t)i];
    const int src = e2.x, tgt = e2.y;
    const float4 as4 = *(const float4*)&attn_self[(size_t)tgt * 4];
    const float4 an4 = *(const float4*)&attn_nei[(size_t)src * 4];
    const float4 m4  = *(const float4*)&m_arr[(size_t)tgt * 4];
    const float4 iv4 = *(const float4*)&inv_arr[(size_t)tgt * 4];
    float4 a;
    a.x = expf(LEAKY(as4.x + an4.x) - m4.x) * iv4.x;
    a.y = expf(LEAKY(as4.y + an4.y) - m4.y) * iv4.y;
    a.z = expf(LEAKY(as4.z + an4.z) - m4.z) * iv4.z;
    a.w = expf(LEAKY(as4.w + an4.w) - m4.w) * iv4.w;
    *(float4*)&alpha_out[(size_t)i * 4] = a;
}

// ---------------------------------------------------------------------------
extern "C" void kernel_launch(void* const* d_in, const int* in_sizes, int n_in,
                              void* d_out, int out_size, void* d_ws, size_t ws_size,
                              hipStream_t stream)
{
    const float* x    = (const float*)d_in[0];
    const int*   ei   = (const int*)d_in[1];
    const float* W    = (const float*)d_in[2];
    const float* aks  = (const float*)d_in[3];
    const float* akn  = (const float*)d_in[4];
    const float* bias = (const float*)d_in[5];

    const int N = in_sizes[0] / 128;
    const int E = in_sizes[1] / 2;

    float* out       = (float*)d_out;
    float* alpha_out = out + (size_t)N * 128;

    char* p = (char*)d_ws;
    auto alloc = [&](size_t bytes) {
        char* r = p;
        p += (bytes + 255) & ~(size_t)255;
        return r;
    };
    float* xp        = (float*)alloc((size_t)N * 128 * 4);
    float* attn_self = (float*)alloc((size_t)N * 4 * 4);
    float* attn_nei  = (float*)alloc((size_t)N * 4 * 4);
    float* m_arr     = (float*)alloc((size_t)N * 4 * 4);
    float* inv_arr   = (float*)alloc((size_t)N * 4 * 4);
    int*   counts    = (int*)alloc((size_t)N * 4);
    int*   cursor    = (int*)alloc((size_t)N * 4);
    int*   offsets   = (int*)alloc((size_t)(N + 1) * 4);
    int*   edge_list = (int*)alloc((size_t)E * 4);
    const int numTiles = (N + 1023) / 1024;
    int*   tileSums  = (int*)alloc((size_t)numTiles * 4);
    int*   tileOffs  = (int*)alloc((size_t)(numTiles + 1) * 4);

    hipMemsetAsync(counts, 0, (size_t)N * 4, stream);
    hipMemsetAsync(cursor, 0, (size_t)N * 4, stream);

    gemm_attn<<<(N + 31) / 32, 256, 0, stream>>>(x, W, aks, akn, xp, attn_self, attn_nei, N);
    hist_kernel<<<(E + 255) / 256, 256, 0, stream>>>(ei, counts, E);
    scan1<<<numTiles, 256, 0, stream>>>(counts, offsets, tileSums, N);
    scan2<<<1, 64, 0, stream>>>(tileSums, tileOffs, numTiles);
    scan3<<<(N + 255) / 256, 256, 0, stream>>>(offsets, tileOffs, N);
    fill_kernel<<<(E + 255) / 256, 256, 0, stream>>>(ei, offsets, cursor, edge_list, E);
    aggregate<<<(N + 3) / 4, 256, 0, stream>>>(ei, offsets, edge_list, xp, attn_self,
                                               attn_nei, bias, out, alpha_out,
                                               m_arr, inv_arr, N, E);
    alpha_kernel<<<(E + 255) / 256, 256, 0, stream>>>(ei, attn_self, attn_nei,
                                                      m_arr, inv_arr, alpha_out, E);
}

// Round 2
// 397.298 us; speedup vs baseline: 1.4694x; 1.4694x over previous
//
#include <hip/hip_runtime.h>
#include <math.h>

#define LEAKY(x) ((x) >= 0.0f ? (x) : 0.2f * (x))

// ---------------------------------------------------------------------------
// Kernel 1: xp = x @ W  (N x 128) = (N x 128)(128 x 128), fused with
// attn_self / attn_neigh = einsum('nhc,ch->nh').
// ---------------------------------------------------------------------------
__global__ __launch_bounds__(256) void gemm_attn(
    const float* __restrict__ x, const float* __restrict__ W,
    const float* __restrict__ aks, const float* __restrict__ akn,
    float* __restrict__ xp, float* __restrict__ attn_self,
    float* __restrict__ attn_nei, int N)
{
    __shared__ float xs[32][132];
    const int t  = threadIdx.x;
    const int nb = blockIdx.x * 32;

    #pragma unroll
    for (int k = 0; k < 16; ++k) {
        int idx = t + k * 256;
        int n = idx >> 7, f = idx & 127;
        xs[n][f] = (nb + n < N) ? x[(size_t)(nb + n) * 128 + f] : 0.0f;
    }
    __syncthreads();

    const int c4 = (t & 31) * 4;     // output column quad (h*32+c)
    const int g  = (t >> 5) * 4;     // first of 4 nodes this thread owns
    float acc[4][4] = {};
    for (int f = 0; f < 128; ++f) {
        const float4 w = *(const float4*)&W[f * 128 + c4];
        #pragma unroll
        for (int i = 0; i < 4; ++i) {
            float xv = xs[g + i][f];
            acc[i][0] = fmaf(xv, w.x, acc[i][0]);
            acc[i][1] = fmaf(xv, w.y, acc[i][1]);
            acc[i][2] = fmaf(xv, w.z, acc[i][2]);
            acc[i][3] = fmaf(xv, w.w, acc[i][3]);
        }
    }
    #pragma unroll
    for (int i = 0; i < 4; ++i) {
        int n = nb + g + i;
        if (n < N)
            *(float4*)&xp[(size_t)n * 128 + c4] =
                make_float4(acc[i][0], acc[i][1], acc[i][2], acc[i][3]);
    }
    __syncthreads();            // everyone done reading x tile
    #pragma unroll
    for (int i = 0; i < 4; ++i) {
        xs[g + i][c4 + 0] = acc[i][0];
        xs[g + i][c4 + 1] = acc[i][1];
        xs[g + i][c4 + 2] = acc[i][2];
        xs[g + i][c4 + 3] = acc[i][3];
    }
    __syncthreads();
    if (t < 128) {
        int n = t >> 2, h = t & 3;
        if (nb + n < N) {
            float ss = 0.0f, sn = 0.0f;
            #pragma unroll
            for (int c = 0; c < 32; ++c) {
                float v = xs[n][h * 32 + c];
                ss = fmaf(v, aks[c * 4 + h], ss);
                sn = fmaf(v, akn[c * 4 + h], sn);
            }
            attn_self[(size_t)(nb + n) * 4 + h] = ss;
            attn_nei [(size_t)(nb + n) * 4 + h] = sn;
        }
    }
}

// ---------------------------------------------------------------------------
// CSR build: histogram -> scan (3 kernels) -> fill (with fused per-edge exp)
// ---------------------------------------------------------------------------
__global__ void hist_kernel(const int* __restrict__ ei, int* __restrict__ counts, int E)
{
    const int i = blockIdx.x * 256 + threadIdx.x;
    if (i < E) atomicAdd(&counts[ei[2 * (size_t)i + 1]], 1);
}

__global__ __launch_bounds__(256) void scan1(
    const int* __restrict__ counts, int* __restrict__ offsets,
    int* __restrict__ tileSums, int N)
{
    __shared__ int sdata[256];
    const int t = threadIdx.x;
    const int i0 = blockIdx.x * 1024 + t * 4;
    int v[4];
    #pragma unroll
    for (int k = 0; k < 4; ++k) v[k] = (i0 + k < N) ? counts[i0 + k] : 0;
    v[1] += v[0]; v[2] += v[1]; v[3] += v[2];
    const int tot = v[3];
    sdata[t] = tot;
    __syncthreads();
    for (int d = 1; d < 256; d <<= 1) {
        int add = (t >= d) ? sdata[t - d] : 0;
        __syncthreads();
        sdata[t] += add;
        __syncthreads();
    }
    const int excl = sdata[t] - tot;
    #pragma unroll
    for (int k = 0; k < 4; ++k) {
        int i = i0 + k;
        if (i < N) offsets[i + 1] = excl + v[k];
    }
    if (t == 255) tileSums[blockIdx.x] = sdata[255];
}

// parallel tile-offset scan (numTiles <= 256)
__global__ __launch_bounds__(256) void scan2(
    const int* __restrict__ tileSums, int* __restrict__ tileOffs, int numTiles)
{
    __shared__ int s[256];
    const int t = threadIdx.x;
    const int v = (t < numTiles) ? tileSums[t] : 0;
    s[t] = v;
    __syncthreads();
    for (int d = 1; d < 256; d <<= 1) {
        int add = (t >= d) ? s[t - d] : 0;
        __syncthreads();
        s[t] += add;
        __syncthreads();
    }
    if (t <= numTiles) tileOffs[t] = (t < numTiles) ? s[t] - v : s[numTiles ? numTiles - 1 : 0];
}

__global__ void scan3(int* __restrict__ offsets, const int* __restrict__ tileOffs, int N)
{
    const int i = blockIdx.x * 256 + threadIdx.x;
    if (i == 0) offsets[0] = 0;
    if (i < N) offsets[i + 1] += tileOffs[i >> 10];
}

// fill CSR with src id AND precomputed ev4 = exp(leaky(as[tgt]+an[src]))
// (no max subtraction: logits are bounded ~|1.5|, exp is safe in f32)
__global__ __launch_bounds__(256) void fill2(
    const int* __restrict__ ei, const int* __restrict__ offsets,
    int* __restrict__ cursor, const float* __restrict__ attn_self,
    const float* __restrict__ attn_nei, int* __restrict__ csr_src,
    float4* __restrict__ csr_ev, int E)
{
    const int i = blockIdx.x * 256 + threadIdx.x;
    if (i >= E) return;
    const int2 e2 = ((const int2*)ei)[i];
    const int src = e2.x, tgt = e2.y;
    const int slot = atomicAdd(&cursor[tgt], 1);
    const int pos  = offsets[tgt] + slot;
    const float4 a4 = *(const float4*)&attn_self[(size_t)tgt * 4];
    const float4 n4 = *(const float4*)&attn_nei[(size_t)src * 4];
    float4 ev;
    ev.x = __expf(LEAKY(a4.x + n4.x));
    ev.y = __expf(LEAKY(a4.y + n4.y));
    ev.z = __expf(LEAKY(a4.z + n4.z));
    ev.w = __expf(LEAKY(a4.w + n4.w));
    csr_src[pos] = src;
    csr_ev[pos]  = ev;
}

__device__ __forceinline__ float pick(const float4& v, int h)
{
    const float ab = (h & 1) ? v.y : v.x;
    const float cd = (h & 1) ? v.w : v.z;
    return (h & 2) ? cd : ab;
}

// ---------------------------------------------------------------------------
// Kernel 3: one wave per node. Streams sequential csr_src/csr_ev (scalar
// path), gathers xp rows (vector path) unrolled x4 for MLP.
// out = (sum_e ev*xp[src] + eS*xp[node]) / sum(ev) + bias.
// ---------------------------------------------------------------------------
__global__ __launch_bounds__(256) void aggregate(
    const int* __restrict__ csr_src, const float4* __restrict__ csr_ev,
    const int* __restrict__ offsets, const float* __restrict__ xp,
    const float* __restrict__ attn_self, const float* __restrict__ attn_nei,
    const float* __restrict__ bias, float* __restrict__ out,
    float* __restrict__ alpha_out, float* __restrict__ inv_arr, int N, int E)
{
    const int lane = threadIdx.x & 63;
    int node = blockIdx.x * 4 + (threadIdx.x >> 6);
    if (node >= N) return;
    node = __builtin_amdgcn_readfirstlane(node);

    const int hL = lane >> 4;        // head of this lane's 2 channels
    const int c0 = 2 * lane;

    const float asH = attn_self[(size_t)node * 4 + hL];
    const float anH = attn_nei [(size_t)node * 4 + hL];
    const float eS  = __expf(LEAKY(asH + anH));
    float sumE = eS;
    const float2 xv = *(const float2*)&xp[(size_t)node * 128 + c0];
    float acc0 = eS * xv.x, acc1 = eS * xv.y;

    const int off0 = __builtin_amdgcn_readfirstlane(offsets[node]);
    const int deg  = __builtin_amdgcn_readfirstlane(offsets[node + 1]) - off0;
    const int*    srcp = csr_src + off0;
    const float4* evp  = csr_ev + off0;

    int j = 0;
    for (; j + 4 <= deg; j += 4) {
        const int s0 = srcp[j + 0], s1 = srcp[j + 1];
        const int s2 = srcp[j + 2], s3 = srcp[j + 3];
        const float4 e0 = evp[j + 0], e1 = evp[j + 1];
        const float4 e2 = evp[j + 2], e3 = evp[j + 3];
        const float2 x0 = *(const float2*)&xp[(size_t)s0 * 128 + c0];
        const float2 x1 = *(const float2*)&xp[(size_t)s1 * 128 + c0];
        const float2 x2 = *(const float2*)&xp[(size_t)s2 * 128 + c0];
        const float2 x3 = *(const float2*)&xp[(size_t)s3 * 128 + c0];
        const float v0 = pick(e0, hL), v1 = pick(e1, hL);
        const float v2 = pick(e2, hL), v3 = pick(e3, hL);
        sumE += (v0 + v1) + (v2 + v3);
        acc0 = fmaf(v0, x0.x, acc0); acc1 = fmaf(v0, x0.y, acc1);
        acc0 = fmaf(v1, x1.x, acc0); acc1 = fmaf(v1, x1.y, acc1);
        acc0 = fmaf(v2, x2.x, acc0); acc1 = fmaf(v2, x2.y, acc1);
        acc0 = fmaf(v3, x3.x, acc0); acc1 = fmaf(v3, x3.y, acc1);
    }
    for (; j < deg; ++j) {
        const int s0 = srcp[j];
        const float v0 = pick(evp[j], hL);
        const float2 x0 = *(const float2*)&xp[(size_t)s0 * 128 + c0];
        sumE += v0;
        acc0 = fmaf(v0, x0.x, acc0); acc1 = fmaf(v0, x0.y, acc1);
    }

    const float inv = 1.0f / sumE;
    *(float2*)&out[(size_t)node * 128 + c0] =
        make_float2(fmaf(acc0, inv, bias[c0]), fmaf(acc1, inv, bias[c0 + 1]));
    if ((lane & 15) == 0) {
        inv_arr[(size_t)node * 4 + hL] = inv;
        alpha_out[(size_t)(E + node) * 4 + hL] = eS * inv;   // self-loop alpha
    }
}

// ---------------------------------------------------------------------------
// Kernel 4: alpha for the E real edges, coalesced by edge id (overwrites the
// csr_ev scratch that lived in this region).
// ---------------------------------------------------------------------------
__global__ __launch_bounds__(256) void alpha_kernel(
    const int* __restrict__ ei, const float* __restrict__ attn_self,
    const float* __restrict__ attn_nei, const float* __restrict__ inv_arr,
    float* __restrict__ alpha_out, int E)
{
    const int i = blockIdx.x * 256 + threadIdx.x;
    if (i >= E) return;
    const int2 e2 = ((const int2*)ei)[i];
    const int src = e2.x, tgt = e2.y;
    const float4 as4 = *(const float4*)&attn_self[(size_t)tgt * 4];
    const float4 an4 = *(const float4*)&attn_nei[(size_t)src * 4];
    const float4 iv4 = *(const float4*)&inv_arr[(size_t)tgt * 4];
    float4 a;
    a.x = __expf(LEAKY(as4.x + an4.x)) * iv4.x;
    a.y = __expf(LEAKY(as4.y + an4.y)) * iv4.y;
    a.z = __expf(LEAKY(as4.z + an4.z)) * iv4.z;
    a.w = __expf(LEAKY(as4.w + an4.w)) * iv4.w;
    *(float4*)&alpha_out[(size_t)i * 4] = a;
}

// ---------------------------------------------------------------------------
extern "C" void kernel_launch(void* const* d_in, const int* in_sizes, int n_in,
                              void* d_out, int out_size, void* d_ws, size_t ws_size,
                              hipStream_t stream)
{
    const float* x    = (const float*)d_in[0];
    const int*   ei   = (const int*)d_in[1];
    const float* W    = (const float*)d_in[2];
    const float* aks  = (const float*)d_in[3];
    const float* akn  = (const float*)d_in[4];
    const float* bias = (const float*)d_in[5];

    const int N = in_sizes[0] / 128;
    const int E = in_sizes[1] / 2;

    float* out       = (float*)d_out;
    float* alpha_out = out + (size_t)N * 128;
    // csr_ev scratch lives in the alpha region of d_out: written by fill2,
    // read by aggregate (slots [0,E)), then overwritten by alpha_kernel.
    float4* csr_ev   = (float4*)alpha_out;

    char* p = (char*)d_ws;
    auto alloc = [&](size_t bytes) {
        char* r = p;
        p += (bytes + 255) & ~(size_t)255;
        return r;
    };
    float* xp        = (float*)alloc((size_t)N * 128 * 4);
    float* attn_self = (float*)alloc((size_t)N * 4 * 4);
    float* attn_nei  = (float*)alloc((size_t)N * 4 * 4);
    float* inv_arr   = (float*)alloc((size_t)N * 4 * 4);
    int*   counts    = (int*)alloc((size_t)N * 4);
    int*   cursor    = (int*)alloc((size_t)N * 4);
    int*   offsets   = (int*)alloc((size_t)(N + 1) * 4);
    int*   csr_src   = (int*)alloc((size_t)E * 4);
    const int numTiles = (N + 1023) / 1024;
    int*   tileSums  = (int*)alloc((size_t)numTiles * 4);
    int*   tileOffs  = (int*)alloc((size_t)(numTiles + 1) * 4);

    hipMemsetAsync(counts, 0, (size_t)N * 4, stream);
    hipMemsetAsync(cursor, 0, (size_t)N * 4, stream);

    gemm_attn<<<(N + 31) / 32, 256, 0, stream>>>(x, W, aks, akn, xp, attn_self, attn_nei, N);
    hist_kernel<<<(E + 255) / 256, 256, 0, stream>>>(ei, counts, E);
    scan1<<<numTiles, 256, 0, stream>>>(counts, offsets, tileSums, N);
    scan2<<<1, 256, 0, stream>>>(tileSums, tileOffs, numTiles);
    scan3<<<(N + 255) / 256, 256, 0, stream>>>(offsets, tileOffs, N);
    fill2<<<(E + 255) / 256, 256, 0, stream>>>(ei, offsets, cursor, attn_self,
                                               attn_nei, csr_src, csr_ev, E);
    aggregate<<<(N + 3) / 4, 256, 0, stream>>>(csr_src, csr_ev, offsets, xp,
                                               attn_self, attn_nei, bias, out,
                                               alpha_out, inv_arr, N, E);
    alpha_kernel<<<(E + 255) / 256, 256, 0, stream>>>(ei, attn_self, attn_nei,
                                                      inv_arr, alpha_out, E);
}

// Round 3
// 326.121 us; speedup vs baseline: 1.7901x; 1.2183x over previous
//
#include <hip/hip_runtime.h>
#include <hip/hip_bf16.h>
#include <math.h>

#define LEAKY(x) ((x) >= 0.0f ? (x) : 0.2f * (x))

__device__ __forceinline__ float bf_lo(uint32_t u) { return __uint_as_float(u << 16); }
__device__ __forceinline__ float bf_hi(uint32_t u) { return __uint_as_float(u & 0xffff0000u); }
__device__ __forceinline__ uint32_t pack2(float a, float b) {
    __hip_bfloat162 h = __float22bfloat162_rn(make_float2(a, b));
    return *reinterpret_cast<uint32_t*>(&h);
}

// ---------------------------------------------------------------------------
// Kernel 1 (fused): blocks [0, gemmBlocks) do xp_bf16 = bf16(x @ W) plus
// attn_self/attn_neigh; blocks [gemmBlocks, ...) do the target histogram.
// ---------------------------------------------------------------------------
__global__ __launch_bounds__(256) void gemm_hist(
    const float* __restrict__ x, const float* __restrict__ W,
    const float* __restrict__ aks, const float* __restrict__ akn,
    uint32_t* __restrict__ xpb, float* __restrict__ attn_self,
    float* __restrict__ attn_nei, const int* __restrict__ ei,
    int* __restrict__ counts, int gemmBlocks, int N, int E)
{
    if (blockIdx.x >= gemmBlocks) {           // histogram part
        const int i = (blockIdx.x - gemmBlocks) * 256 + threadIdx.x;
        if (i < E) atomicAdd(&counts[ei[2 * (size_t)i + 1]], 1);
        return;
    }

    __shared__ float xs[32][132];
    const int t  = threadIdx.x;
    const int nb = blockIdx.x * 32;

    #pragma unroll
    for (int k = 0; k < 16; ++k) {
        int idx = t + k * 256;
        int n = idx >> 7, f = idx & 127;
        xs[n][f] = (nb + n < N) ? x[(size_t)(nb + n) * 128 + f] : 0.0f;
    }
    __syncthreads();

    const int c4 = (t & 31) * 4;     // output column quad (h*32+c)
    const int g  = (t >> 5) * 4;     // first of 4 nodes this thread owns
    float acc[4][4] = {};
    for (int f = 0; f < 128; ++f) {
        const float4 w = *(const float4*)&W[f * 128 + c4];
        #pragma unroll
        for (int i = 0; i < 4; ++i) {
            float xv = xs[g + i][f];
            acc[i][0] = fmaf(xv, w.x, acc[i][0]);
            acc[i][1] = fmaf(xv, w.y, acc[i][1]);
            acc[i][2] = fmaf(xv, w.z, acc[i][2]);
            acc[i][3] = fmaf(xv, w.w, acc[i][3]);
        }
    }
    #pragma unroll
    for (int i = 0; i < 4; ++i) {
        int n = nb + g + i;
        if (n < N)
            *(uint2*)&xpb[(size_t)n * 64 + (c4 >> 1)] =
                make_uint2(pack2(acc[i][0], acc[i][1]), pack2(acc[i][2], acc[i][3]));
    }
    __syncthreads();            // everyone done reading x tile
    #pragma unroll
    for (int i = 0; i < 4; ++i) {
        xs[g + i][c4 + 0] = acc[i][0];
        xs[g + i][c4 + 1] = acc[i][1];
        xs[g + i][c4 + 2] = acc[i][2];
        xs[g + i][c4 + 3] = acc[i][3];
    }
    __syncthreads();
    if (t < 128) {
        int n = t >> 2, h = t & 3;
        if (nb + n < N) {
            float ss = 0.0f, sn = 0.0f;
            #pragma unroll
            for (int c = 0; c < 32; ++c) {
                float v = xs[n][h * 32 + c];
                ss = fmaf(v, aks[c * 4 + h], ss);
                sn = fmaf(v, akn[c * 4 + h], sn);
            }
            attn_self[(size_t)(nb + n) * 4 + h] = ss;
            attn_nei [(size_t)(nb + n) * 4 + h] = sn;
        }
    }
}

// ---------------------------------------------------------------------------
// CSR scan: offsets = exclusive prefix of counts
// ---------------------------------------------------------------------------
__global__ __launch_bounds__(256) void scan1(
    const int* __restrict__ counts, int* __restrict__ offsets,
    int* __restrict__ tileSums, int N)
{
    __shared__ int sdata[256];
    const int t = threadIdx.x;
    const int i0 = blockIdx.x * 1024 + t * 4;
    int v[4];
    #pragma unroll
    for (int k = 0; k < 4; ++k) v[k] = (i0 + k < N) ? counts[i0 + k] : 0;
    v[1] += v[0]; v[2] += v[1]; v[3] += v[2];
    const int tot = v[3];
    sdata[t] = tot;
    __syncthreads();
    for (int d = 1; d < 256; d <<= 1) {
        int add = (t >= d) ? sdata[t - d] : 0;
        __syncthreads();
        sdata[t] += add;
        __syncthreads();
    }
    const int excl = sdata[t] - tot;
    #pragma unroll
    for (int k = 0; k < 4; ++k) {
        int i = i0 + k;
        if (i < N) offsets[i + 1] = excl + v[k];
    }
    if (t == 255) tileSums[blockIdx.x] = sdata[255];
}

__global__ __launch_bounds__(256) void scan2(
    const int* __restrict__ tileSums, int* __restrict__ tileOffs, int numTiles)
{
    __shared__ int s[256];
    const int t = threadIdx.x;
    const int v = (t < numTiles) ? tileSums[t] : 0;
    s[t] = v;
    __syncthreads();
    for (int d = 1; d < 256; d <<= 1) {
        int add = (t >= d) ? s[t - d] : 0;
        __syncthreads();
        s[t] += add;
        __syncthreads();
    }
    if (t < numTiles) tileOffs[t] = s[t] - v;
}

__global__ void scan3(int* __restrict__ offsets, const int* __restrict__ tileOffs, int N)
{
    const int i = blockIdx.x * 256 + threadIdx.x;
    if (i == 0) offsets[0] = 0;
    if (i < N) offsets[i + 1] += tileOffs[i >> 10];
}

// ---------------------------------------------------------------------------
// fill2: scatter {src, ev4=exp(leaky(as[tgt]+an[src]))} into CSR order.
// Slots allocated by counting `counts` DOWN (no cursor array needed).
// ---------------------------------------------------------------------------
__global__ __launch_bounds__(256) void fill2(
    const int* __restrict__ ei, const int* __restrict__ offsets,
    int* __restrict__ counts, const float* __restrict__ attn_self,
    const float* __restrict__ attn_nei, int* __restrict__ csr_src,
    float4* __restrict__ csr_ev, int E)
{
    const int i = blockIdx.x * 256 + threadIdx.x;
    if (i >= E) return;
    const int2 e2 = ((const int2*)ei)[i];
    const int src = e2.x, tgt = e2.y;
    const int slot = atomicSub(&counts[tgt], 1) - 1;
    const int pos  = offsets[tgt] + slot;
    const float4 a4 = *(const float4*)&attn_self[(size_t)tgt * 4];
    const float4 n4 = *(const float4*)&attn_nei[(size_t)src * 4];
    float4 ev;
    ev.x = __expf(LEAKY(a4.x + n4.x));
    ev.y = __expf(LEAKY(a4.y + n4.y));
    ev.z = __expf(LEAKY(a4.z + n4.z));
    ev.w = __expf(LEAKY(a4.w + n4.w));
    csr_src[pos] = src;
    csr_ev[pos]  = ev;
}

__device__ __forceinline__ float pick(const float4& v, int h)
{
    const float ab = (h & 1) ? v.y : v.x;
    const float cd = (h & 1) ? v.w : v.z;
    return (h & 2) ? cd : ab;
}

// ---------------------------------------------------------------------------
// Kernel 3: one wave per node. Sequential csr stream (scalar path) +
// bf16 xp gathers (4 B/lane), masked unroll-4 so every group is full.
// ---------------------------------------------------------------------------
__global__ __launch_bounds__(256) void aggregate(
    const int* __restrict__ csr_src, const float4* __restrict__ csr_ev,
    const int* __restrict__ offsets, const uint32_t* __restrict__ xpb,
    const float* __restrict__ attn_self, const float* __restrict__ attn_nei,
    const float* __restrict__ bias, float* __restrict__ out,
    float* __restrict__ alpha_out, float* __restrict__ inv_arr, int N, int E)
{
    const int lane = threadIdx.x & 63;
    int node = blockIdx.x * 4 + (threadIdx.x >> 6);
    if (node >= N) return;
    node = __builtin_amdgcn_readfirstlane(node);

    const int hL = lane >> 4;        // head of this lane's 2 channels
    const int c0 = 2 * lane;

    const float asH = attn_self[(size_t)node * 4 + hL];
    const float anH = attn_nei [(size_t)node * 4 + hL];
    const float eS  = __expf(LEAKY(asH + anH));
    float sumE = eS;
    const uint32_t uS = xpb[(size_t)node * 64 + lane];
    float acc0 = eS * bf_lo(uS), acc1 = eS * bf_hi(uS);

    const int off0 = __builtin_amdgcn_readfirstlane(offsets[node]);
    const int deg  = __builtin_amdgcn_readfirstlane(offsets[node + 1]) - off0;
    const int*    srcp = csr_src + off0;
    const float4* evp  = csr_ev + off0;

    for (int j = 0; j < deg; j += 4) {
        const int i1 = min(j + 1, deg - 1);
        const int i2 = min(j + 2, deg - 1);
        const int i3 = min(j + 3, deg - 1);
        const int s0 = srcp[j], s1 = srcp[i1], s2 = srcp[i2], s3 = srcp[i3];
        const float4 e0 = evp[j], e1 = evp[i1], e2 = evp[i2], e3 = evp[i3];
        const uint32_t u0 = xpb[(size_t)s0 * 64 + lane];
        const uint32_t u1 = xpb[(size_t)s1 * 64 + lane];
        const uint32_t u2 = xpb[(size_t)s2 * 64 + lane];
        const uint32_t u3 = xpb[(size_t)s3 * 64 + lane];
        const float v0 = pick(e0, hL);
        const float v1 = (j + 1 < deg) ? pick(e1, hL) : 0.0f;
        const float v2 = (j + 2 < deg) ? pick(e2, hL) : 0.0f;
        const float v3 = (j + 3 < deg) ? pick(e3, hL) : 0.0f;
        sumE += (v0 + v1) + (v2 + v3);
        acc0 = fmaf(v0, bf_lo(u0), acc0); acc1 = fmaf(v0, bf_hi(u0), acc1);
        acc0 = fmaf(v1, bf_lo(u1), acc0); acc1 = fmaf(v1, bf_hi(u1), acc1);
        acc0 = fmaf(v2, bf_lo(u2), acc0); acc1 = fmaf(v2, bf_hi(u2), acc1);
        acc0 = fmaf(v3, bf_lo(u3), acc0); acc1 = fmaf(v3, bf_hi(u3), acc1);
    }

    const float inv = 1.0f / sumE;
    *(float2*)&out[(size_t)node * 128 + c0] =
        make_float2(fmaf(acc0, inv, bias[c0]), fmaf(acc1, inv, bias[c0 + 1]));
    if ((lane & 15) == 0) {
        inv_arr[(size_t)node * 4 + hL] = inv;
        alpha_out[(size_t)(E + node) * 4 + hL] = eS * inv;   // self-loop alpha
    }
}

// ---------------------------------------------------------------------------
// Kernel 4: alpha for the E real edges, coalesced by edge id (overwrites the
// csr_ev scratch that lived in this region).
// ---------------------------------------------------------------------------
__global__ __launch_bounds__(256) void alpha_kernel(
    const int* __restrict__ ei, const float* __restrict__ attn_self,
    const float* __restrict__ attn_nei, const float* __restrict__ inv_arr,
    float* __restrict__ alpha_out, int E)
{
    const int i = blockIdx.x * 256 + threadIdx.x;
    if (i >= E) return;
    const int2 e2 = ((const int2*)ei)[i];
    const int src = e2.x, tgt = e2.y;
    const float4 as4 = *(const float4*)&attn_self[(size_t)tgt * 4];
    const float4 an4 = *(const float4*)&attn_nei[(size_t)src * 4];
    const float4 iv4 = *(const float4*)&inv_arr[(size_t)tgt * 4];
    float4 a;
    a.x = __expf(LEAKY(as4.x + an4.x)) * iv4.x;
    a.y = __expf(LEAKY(as4.y + an4.y)) * iv4.y;
    a.z = __expf(LEAKY(as4.z + an4.z)) * iv4.z;
    a.w = __expf(LEAKY(as4.w + an4.w)) * iv4.w;
    *(float4*)&alpha_out[(size_t)i * 4] = a;
}

// ---------------------------------------------------------------------------
extern "C" void kernel_launch(void* const* d_in, const int* in_sizes, int n_in,
                              void* d_out, int out_size, void* d_ws, size_t ws_size,
                              hipStream_t stream)
{
    const float* x    = (const float*)d_in[0];
    const int*   ei   = (const int*)d_in[1];
    const float* W    = (const float*)d_in[2];
    const float* aks  = (const float*)d_in[3];
    const float* akn  = (const float*)d_in[4];
    const float* bias = (const float*)d_in[5];

    const int N = in_sizes[0] / 128;
    const int E = in_sizes[1] / 2;

    float* out       = (float*)d_out;
    float* alpha_out = out + (size_t)N * 128;
    // csr_ev scratch lives in the alpha region of d_out (bytes [0, E*16)):
    // written by fill2, read by aggregate, then overwritten by alpha_kernel.
    // Self-loop alphas live at byte offset E*16 onward — no overlap.
    float4* csr_ev   = (float4*)alpha_out;

    char* p = (char*)d_ws;
    auto alloc = [&](size_t bytes) {
        char* r = p;
        p += (bytes + 255) & ~(size_t)255;
        return r;
    };
    uint32_t* xpb      = (uint32_t*)alloc((size_t)N * 64 * 4);   // bf16x2 per entry
    float* attn_self   = (float*)alloc((size_t)N * 4 * 4);
    float* attn_nei    = (float*)alloc((size_t)N * 4 * 4);
    float* inv_arr     = (float*)alloc((size_t)N * 4 * 4);
    int*   counts      = (int*)alloc((size_t)N * 4);
    int*   offsets     = (int*)alloc((size_t)(N + 1) * 4);
    int*   csr_src     = (int*)alloc((size_t)E * 4);
    const int numTiles = (N + 1023) / 1024;
    int*   tileSums    = (int*)alloc((size_t)numTiles * 4);
    int*   tileOffs    = (int*)alloc((size_t)numTiles * 4);

    hipMemsetAsync(counts, 0, (size_t)N * 4, stream);

    const int gemmBlocks = (N + 31) / 32;
    const int histBlocks = (E + 255) / 256;
    gemm_hist<<<gemmBlocks + histBlocks, 256, 0, stream>>>(
        x, W, aks, akn, xpb, attn_self, attn_nei, ei, counts, gemmBlocks, N, E);
    scan1<<<numTiles, 256, 0, stream>>>(counts, offsets, tileSums, N);
    scan2<<<1, 256, 0, stream>>>(tileSums, tileOffs, numTiles);
    scan3<<<(N + 255) / 256, 256, 0, stream>>>(offsets, tileOffs, N);
    fill2<<<(E + 255) / 256, 256, 0, stream>>>(ei, offsets, counts, attn_self,
                                               attn_nei, csr_src, csr_ev, E);
    aggregate<<<(N + 3) / 4, 256, 0, stream>>>(csr_src, csr_ev, offsets, xpb,
                                               attn_self, attn_nei, bias, out,
                                               alpha_out, inv_arr, N, E);
    alpha_kernel<<<(E + 255) / 256, 256, 0, stream>>>(ei, attn_self, attn_nei,
                                                      inv_arr, alpha_out, E);
}

// Round 4
// 292.914 us; speedup vs baseline: 1.9931x; 1.1134x over previous
//
#include <hip/hip_runtime.h>
#include <hip/hip_bf16.h>
#include <math.h>

#define LEAKY(x) ((x) >= 0.0f ? (x) : 0.2f * (x))

typedef __attribute__((ext_vector_type(8))) short short8;
typedef __attribute__((ext_vector_type(4))) float f32x4;

__device__ __forceinline__ float bf_lo(uint32_t u) { return __uint_as_float(u << 16); }
__device__ __forceinline__ float bf_hi(uint32_t u) { return __uint_as_float(u & 0xffff0000u); }
__device__ __forceinline__ uint32_t pack2(float a, float b) {
    __hip_bfloat162 h = __float22bfloat162_rn(make_float2(a, b));
    return *reinterpret_cast<uint32_t*>(&h);
}

// ---------------------------------------------------------------------------
// w_prep: pack W (f32 [128 k][128 col]) into bf16 MFMA B-fragment order:
// slot = (kb*8+cb)*64 + lane, 16 B per slot = 8 bf16 (k = kb*32+(l>>4)*8+j,
// col = cb*16+(l&15)). 2048 slots = 32 KB.
// ---------------------------------------------------------------------------
__global__ __launch_bounds__(256) void w_prep(
    const float* __restrict__ W, uint32_t* __restrict__ Wp)
{
    const int slot = blockIdx.x * 256 + threadIdx.x;
    if (slot >= 2048) return;
    const int kb = slot >> 9;
    const int cb = (slot >> 6) & 7;
    const int l  = slot & 63;
    const int k0 = kb * 32 + (l >> 4) * 8;
    const int col = cb * 16 + (l & 15);
    uint32_t u[4];
    #pragma unroll
    for (int p = 0; p < 4; ++p) {
        const float a = W[(size_t)(k0 + 2 * p) * 128 + col];
        const float b = W[(size_t)(k0 + 2 * p + 1) * 128 + col];
        u[p] = pack2(a, b);
    }
    *(uint4*)&Wp[(size_t)slot * 4] = make_uint4(u[0], u[1], u[2], u[3]);
}

// ---------------------------------------------------------------------------
// Kernel 1 (fused): blocks [0, gemmBlocks): MFMA GEMM, 64 nodes/block
// (4 waves x 16 rows), xp staged in LDS f32 for attn + bf16 repack.
// Blocks [gemmBlocks, ...): target histogram.
// ---------------------------------------------------------------------------
__global__ __launch_bounds__(256) void gemm_hist(
    const float* __restrict__ x, const uint32_t* __restrict__ Wp,
    const float* __restrict__ aks, const float* __restrict__ akn,
    uint32_t* __restrict__ xpb, float* __restrict__ attn_self,
    float* __restrict__ attn_nei, const int* __restrict__ ei,
    int* __restrict__ counts, int gemmBlocks, int N, int E)
{
    if (blockIdx.x >= gemmBlocks) {           // histogram part
        const int i = (blockIdx.x - gemmBlocks) * 256 + threadIdx.x;
        if (i < E) atomicAdd(&counts[ei[2 * (size_t)i + 1]], 1);
        return;
    }

    __shared__ float xs[64][132];
    const int t  = threadIdx.x;
    const int w  = t >> 6;
    const int l  = t & 63;
    const int nb = blockIdx.x * 64;

    const int row  = nb + w * 16 + (l & 15);
    const int rowc = min(row, N - 1);
    const int kg   = (l >> 4) * 8;
    const float* xrow = x + (size_t)rowc * 128 + kg;

    f32x4 acc[8] = {};
    #pragma unroll
    for (int kb = 0; kb < 4; ++kb) {
        const float4 x0 = *(const float4*)(xrow + kb * 32);
        const float4 x1 = *(const float4*)(xrow + kb * 32 + 4);
        union { short8 s; uint32_t u[4]; } A;
        A.u[0] = pack2(x0.x, x0.y); A.u[1] = pack2(x0.z, x0.w);
        A.u[2] = pack2(x1.x, x1.y); A.u[3] = pack2(x1.z, x1.w);
        #pragma unroll
        for (int cb = 0; cb < 8; ++cb) {
            union { short8 s; uint4 u; } B;
            B.u = *(const uint4*)&Wp[(((size_t)(kb * 8 + cb)) * 64 + l) * 4];
            acc[cb] = __builtin_amdgcn_mfma_f32_16x16x32_bf16(A.s, B.s, acc[cb], 0, 0, 0);
        }
    }

    // D -> LDS (f32): row = (l>>4)*4 + r, col = cb*16 + (l&15)
    const int r0 = (l >> 4) * 4;
    const int cl = l & 15;
    #pragma unroll
    for (int cb = 0; cb < 8; ++cb)
        #pragma unroll
        for (int r = 0; r < 4; ++r)
            xs[w * 16 + r0 + r][cb * 16 + cl] = acc[cb][r];
    __syncthreads();

    // repack 64 nodes x 128 cols -> bf16x2, coalesced
    #pragma unroll
    for (int i = 0; i < 16; ++i) {
        const int idx = t + i * 256;           // 0..4095
        const int n = idx >> 6, q = idx & 63;
        const int gn = nb + n;
        if (gn < N)
            xpb[(size_t)gn * 64 + q] = pack2(xs[n][2 * q], xs[n][2 * q + 1]);
    }

    // attn_self / attn_neigh from f32 xp
    {
        const int n = t >> 2, h = t & 3;
        const int gn = nb + n;
        if (gn < N) {
            float ss = 0.0f, sn = 0.0f;
            #pragma unroll
            for (int c = 0; c < 32; ++c) {
                const float v = xs[n][h * 32 + c];
                ss = fmaf(v, aks[c * 4 + h], ss);
                sn = fmaf(v, akn[c * 4 + h], sn);
            }
            attn_self[(size_t)gn * 4 + h] = ss;
            attn_nei [(size_t)gn * 4 + h] = sn;
        }
    }
}

// ---------------------------------------------------------------------------
// CSR scan: offsets = exclusive prefix of counts
// ---------------------------------------------------------------------------
__global__ __launch_bounds__(256) void scan1(
    const int* __restrict__ counts, int* __restrict__ offsets,
    int* __restrict__ tileSums, int N)
{
    __shared__ int sdata[256];
    const int t = threadIdx.x;
    const int i0 = blockIdx.x * 1024 + t * 4;
    int v[4];
    #pragma unroll
    for (int k = 0; k < 4; ++k) v[k] = (i0 + k < N) ? counts[i0 + k] : 0;
    v[1] += v[0]; v[2] += v[1]; v[3] += v[2];
    const int tot = v[3];
    sdata[t] = tot;
    __syncthreads();
    for (int d = 1; d < 256; d <<= 1) {
        int add = (t >= d) ? sdata[t - d] : 0;
        __syncthreads();
        sdata[t] += add;
        __syncthreads();
    }
    const int excl = sdata[t] - tot;
    #pragma unroll
    for (int k = 0; k < 4; ++k) {
        int i = i0 + k;
        if (i < N) offsets[i + 1] = excl + v[k];
    }
    if (t == 255) tileSums[blockIdx.x] = sdata[255];
}

__global__ __launch_bounds__(256) void scan2(
    const int* __restrict__ tileSums, int* __restrict__ tileOffs, int numTiles)
{
    __shared__ int s[256];
    const int t = threadIdx.x;
    const int v = (t < numTiles) ? tileSums[t] : 0;
    s[t] = v;
    __syncthreads();
    for (int d = 1; d < 256; d <<= 1) {
        int add = (t >= d) ? s[t - d] : 0;
        __syncthreads();
        s[t] += add;
        __syncthreads();
    }
    if (t < numTiles) tileOffs[t] = s[t] - v;
}

__global__ void scan3(int* __restrict__ offsets, const int* __restrict__ tileOffs, int N)
{
    const int i = blockIdx.x * 256 + threadIdx.x;
    if (i == 0) offsets[0] = 0;
    if (i < N) offsets[i + 1] += tileOffs[i >> 10];
}

// ---------------------------------------------------------------------------
// fill2: scatter {src, ev4=exp(leaky(as[tgt]+an[src]))} into CSR order.
// Slots allocated by counting `counts` DOWN (no cursor array needed).
// ---------------------------------------------------------------------------
__global__ __launch_bounds__(256) void fill2(
    const int* __restrict__ ei, const int* __restrict__ offsets,
    int* __restrict__ counts, const float* __restrict__ attn_self,
    const float* __restrict__ attn_nei, int* __restrict__ csr_src,
    float4* __restrict__ csr_ev, int E)
{
    const int i = blockIdx.x * 256 + threadIdx.x;
    if (i >= E) return;
    const int2 e2 = ((const int2*)ei)[i];
    const int src = e2.x, tgt = e2.y;
    const int slot = atomicSub(&counts[tgt], 1) - 1;
    const int pos  = offsets[tgt] + slot;
    const float4 a4 = *(const float4*)&attn_self[(size_t)tgt * 4];
    const float4 n4 = *(const float4*)&attn_nei[(size_t)src * 4];
    float4 ev;
    ev.x = __expf(LEAKY(a4.x + n4.x));
    ev.y = __expf(LEAKY(a4.y + n4.y));
    ev.z = __expf(LEAKY(a4.z + n4.z));
    ev.w = __expf(LEAKY(a4.w + n4.w));
    csr_src[pos] = src;
    csr_ev[pos]  = ev;
}

__device__ __forceinline__ float pick(const float4& v, int h)
{
    const float ab = (h & 1) ? v.y : v.x;
    const float cd = (h & 1) ? v.w : v.z;
    return (h & 2) ? cd : ab;
}

// ---------------------------------------------------------------------------
// Kernel 3: one wave per node. Sequential csr stream (scalar path) +
// bf16 xp gathers (4 B/lane), masked unroll-4 so every group is full.
// ---------------------------------------------------------------------------
__global__ __launch_bounds__(256) void aggregate(
    const int* __restrict__ csr_src, const float4* __restrict__ csr_ev,
    const int* __restrict__ offsets, const uint32_t* __restrict__ xpb,
    const float* __restrict__ attn_self, const float* __restrict__ attn_nei,
    const float* __restrict__ bias, float* __restrict__ out,
    float* __restrict__ alpha_out, float* __restrict__ inv_arr, int N, int E)
{
    const int lane = threadIdx.x & 63;
    int node = blockIdx.x * 4 + (threadIdx.x >> 6);
    if (node >= N) return;
    node = __builtin_amdgcn_readfirstlane(node);

    const int hL = lane >> 4;        // head of this lane's 2 channels
    const int c0 = 2 * lane;

    const float asH = attn_self[(size_t)node * 4 + hL];
    const float anH = attn_nei [(size_t)node * 4 + hL];
    const float eS  = __expf(LEAKY(asH + anH));
    float sumE = eS;
    const uint32_t uS = xpb[(size_t)node * 64 + lane];
    float acc0 = eS * bf_lo(uS), acc1 = eS * bf_hi(uS);

    const int off0 = __builtin_amdgcn_readfirstlane(offsets[node]);
    const int deg  = __builtin_amdgcn_readfirstlane(offsets[node + 1]) - off0;
    const int*    srcp = csr_src + off0;
    const float4* evp  = csr_ev + off0;

    for (int j = 0; j < deg; j += 4) {
        const int i1 = min(j + 1, deg - 1);
        const int i2 = min(j + 2, deg - 1);
        const int i3 = min(j + 3, deg - 1);
        const int s0 = srcp[j], s1 = srcp[i1], s2 = srcp[i2], s3 = srcp[i3];
        const float4 e0 = evp[j], e1 = evp[i1], e2 = evp[i2], e3 = evp[i3];
        const uint32_t u0 = xpb[(size_t)s0 * 64 + lane];
        const uint32_t u1 = xpb[(size_t)s1 * 64 + lane];
        const uint32_t u2 = xpb[(size_t)s2 * 64 + lane];
        const uint32_t u3 = xpb[(size_t)s3 * 64 + lane];
        const float v0 = pick(e0, hL);
        const float v1 = (j + 1 < deg) ? pick(e1, hL) : 0.0f;
        const float v2 = (j + 2 < deg) ? pick(e2, hL) : 0.0f;
        const float v3 = (j + 3 < deg) ? pick(e3, hL) : 0.0f;
        sumE += (v0 + v1) + (v2 + v3);
        acc0 = fmaf(v0, bf_lo(u0), acc0); acc1 = fmaf(v0, bf_hi(u0), acc1);
        acc0 = fmaf(v1, bf_lo(u1), acc0); acc1 = fmaf(v1, bf_hi(u1), acc1);
        acc0 = fmaf(v2, bf_lo(u2), acc0); acc1 = fmaf(v2, bf_hi(u2), acc1);
        acc0 = fmaf(v3, bf_lo(u3), acc0); acc1 = fmaf(v3, bf_hi(u3), acc1);
    }

    const float inv = 1.0f / sumE;
    *(float2*)&out[(size_t)node * 128 + c0] =
        make_float2(fmaf(acc0, inv, bias[c0]), fmaf(acc1, inv, bias[c0 + 1]));
    if ((lane & 15) == 0) {
        inv_arr[(size_t)node * 4 + hL] = inv;
        alpha_out[(size_t)(E + node) * 4 + hL] = eS * inv;   // self-loop alpha
    }
}

// ---------------------------------------------------------------------------
// Kernel 4: alpha for the E real edges, coalesced by edge id (overwrites the
// csr_ev scratch that lived in this region).
// ---------------------------------------------------------------------------
__global__ __launch_bounds__(256) void alpha_kernel(
    const int* __restrict__ ei, const float* __restrict__ attn_self,
    const float* __restrict__ attn_nei, const float* __restrict__ inv_arr,
    float* __restrict__ alpha_out, int E)
{
    const int i = blockIdx.x * 256 + threadIdx.x;
    if (i >= E) return;
    const int2 e2 = ((const int2*)ei)[i];
    const int src = e2.x, tgt = e2.y;
    const float4 as4 = *(const float4*)&attn_self[(size_t)tgt * 4];
    const float4 an4 = *(const float4*)&attn_nei[(size_t)src * 4];
    const float4 iv4 = *(const float4*)&inv_arr[(size_t)tgt * 4];
    float4 a;
    a.x = __expf(LEAKY(as4.x + an4.x)) * iv4.x;
    a.y = __expf(LEAKY(as4.y + an4.y)) * iv4.y;
    a.z = __expf(LEAKY(as4.z + an4.z)) * iv4.z;
    a.w = __expf(LEAKY(as4.w + an4.w)) * iv4.w;
    *(float4*)&alpha_out[(size_t)i * 4] = a;
}

// ---------------------------------------------------------------------------
extern "C" void kernel_launch(void* const* d_in, const int* in_sizes, int n_in,
                              void* d_out, int out_size, void* d_ws, size_t ws_size,
                              hipStream_t stream)
{
    const float* x    = (const float*)d_in[0];
    const int*   ei   = (const int*)d_in[1];
    const float* W    = (const float*)d_in[2];
    const float* aks  = (const float*)d_in[3];
    const float* akn  = (const float*)d_in[4];
    const float* bias = (const float*)d_in[5];

    const int N = in_sizes[0] / 128;
    const int E = in_sizes[1] / 2;

    float* out       = (float*)d_out;
    float* alpha_out = out + (size_t)N * 128;
    // csr_ev scratch lives in the alpha region of d_out (bytes [0, E*16)):
    // written by fill2, read by aggregate, then overwritten by alpha_kernel.
    // Self-loop alphas live at byte offset E*16 onward — no overlap.
    float4* csr_ev   = (float4*)alpha_out;

    char* p = (char*)d_ws;
    auto alloc = [&](size_t bytes) {
        char* r = p;
        p += (bytes + 255) & ~(size_t)255;
        return r;
    };
    uint32_t* xpb      = (uint32_t*)alloc((size_t)N * 64 * 4);   // bf16x2 per entry
    uint32_t* Wp       = (uint32_t*)alloc((size_t)2048 * 16);    // packed bf16 W frags
    float* attn_self   = (float*)alloc((size_t)N * 4 * 4);
    float* attn_nei    = (float*)alloc((size_t)N * 4 * 4);
    float* inv_arr     = (float*)alloc((size_t)N * 4 * 4);
    int*   counts      = (int*)alloc((size_t)N * 4);
    int*   offsets     = (int*)alloc((size_t)(N + 1) * 4);
    int*   csr_src     = (int*)alloc((size_t)E * 4);
    const int numTiles = (N + 1023) / 1024;
    int*   tileSums    = (int*)alloc((size_t)numTiles * 4);
    int*   tileOffs    = (int*)alloc((size_t)numTiles * 4);

    hipMemsetAsync(counts, 0, (size_t)N * 4, stream);

    w_prep<<<8, 256, 0, stream>>>(W, Wp);

    const int gemmBlocks = (N + 63) / 64;
    const int histBlocks = (E + 255) / 256;
    gemm_hist<<<gemmBlocks + histBlocks, 256, 0, stream>>>(
        x, Wp, aks, akn, xpb, attn_self, attn_nei, ei, counts, gemmBlocks, N, E);
    scan1<<<numTiles, 256, 0, stream>>>(counts, offsets, tileSums, N);
    scan2<<<1, 256, 0, stream>>>(tileSums, tileOffs, numTiles);
    scan3<<<(N + 255) / 256, 256, 0, stream>>>(offsets, tileOffs, N);
    fill2<<<(E + 255) / 256, 256, 0, stream>>>(ei, offsets, counts, attn_self,
                                               attn_nei, csr_src, csr_ev, E);
    aggregate<<<(N + 3) / 4, 256, 0, stream>>>(csr_src, csr_ev, offsets, xpb,
                                               attn_self, attn_nei, bias, out,
                                               alpha_out, inv_arr, N, E);
    alpha_kernel<<<(E + 255) / 256, 256, 0, stream>>>(ei, attn_self, attn_nei,
                                                      inv_arr, alpha_out, E);
}